// Round 2
// baseline (657.829 us; speedup 1.0000x reference)
//
#include <hip/hip_runtime.h>
#include <hip/hip_bf16.h>

// Problem constants
#define NB 2
#define NN 512
#define HH 128
#define DD 128
#define TT 8

// ws layout (bytes).
#define WPACK_OFF 0        // ushort[16*144*8] = 36864 B, bf16 [k/8][n][k%8]
#define C_OFF     36864    // float[2*512*128]  z@Wm1 + g@Wmg + (bm1+bm2+bme+bmg)
#define BROW_OFF  561152   // float[2*512*128]  z@Wm2
#define TC_OFF    1085440  // float[2*512*8]    z@Wt1 + g@Wtg + (bt1+bt2+bte+btg)
#define TB_OFF    1118208  // float[2*512*8]    z@Wt2
#define OC_OFF    1150976  // float[2*512*128]  z@Wo1 + bo1 + bo2
#define M1_OFF    1675264  // uint[2*512*128]   order-mapped atomic max of (acc+brw) over adj=1
#define Z_OFF     2199552  // int[2*512]        1 if any sender has adj==0
// memset region: [M1_OFF, Z_OFF+4096) = 528384 bytes

#define OUT_TRI   131072   // float offset of tri_msgs in d_out

typedef float f32x4 __attribute__((ext_vector_type(4)));
typedef short s16x8 __attribute__((ext_vector_type(8)));

__device__ __forceinline__ unsigned short f2bf(float f) {
    union { float f; unsigned int u; } x; x.f = f;
    unsigned int u = x.u;
    unsigned int r = (u + 0x7FFFu + ((u >> 16) & 1u)) >> 16;  // RNE
    return (unsigned short)r;
}

// order-preserving float<->uint mapping for atomic max
__device__ __forceinline__ unsigned fmap(float x) {
    unsigned u = __float_as_uint(x);
    return (u & 0x80000000u) ? ~u : (u | 0x80000000u);
}
__device__ __forceinline__ float funmap(unsigned u) {
    return (u & 0x80000000u) ? __uint_as_float(u & 0x7FFFFFFFu)
                             : __uint_as_float(~u);
}

// ---------------------------------------------------------------------------
// k0: precompute small projections (fp32) + pack bf16 weights for MFMA
// ---------------------------------------------------------------------------
__global__ __launch_bounds__(256) void k0_precompute(
    const float* __restrict__ node, const float* __restrict__ hidden,
    const float* __restrict__ graph,
    const float* __restrict__ Wm1, const float* __restrict__ Wm2,
    const float* __restrict__ Wo1, const float* __restrict__ Wmg,
    const float* __restrict__ Wt1, const float* __restrict__ Wt2,
    const float* __restrict__ Wtg,
    const float* __restrict__ Wme, const float* __restrict__ Wte,
    const float* __restrict__ bm1, const float* __restrict__ bm2,
    const float* __restrict__ bme, const float* __restrict__ bmg,
    const float* __restrict__ bo1, const float* __restrict__ bo2,
    const float* __restrict__ bt1, const float* __restrict__ bt2,
    const float* __restrict__ bte, const float* __restrict__ btg,
    char* __restrict__ ws)
{
    const int bx = blockIdx.x, tid = threadIdx.x;
    if (bx == 256) {
        unsigned short* wp = (unsigned short*)(ws + WPACK_OFF);
        for (int idx = tid; idx < 16 * 144 * 8; idx += 256) {
            int j = idx & 7, tmp = idx >> 3;
            int n = tmp % 144, kq = tmp / 144;
            int k = kq * 8 + j;
            float v = 0.f;
            if (n < 128) v = Wme[k * 128 + n];
            else if (n < 136) v = Wte[k * 8 + (n - 128)];
            wp[idx] = f2bf(v);
        }
        return;
    }
    __shared__ float zs[4 * 257];
    const int row0 = bx * 4;
    const int b = row0 >> 9;
    #pragma unroll
    for (int e = 0; e < 4; e++) {
        int idx = e * 256 + tid;
        int rl = idx >> 8, col = idx & 255;
        float v = (col < 128) ? node[(row0 + rl) * 128 + col]
                              : hidden[(row0 + rl) * 128 + col - 128];
        zs[rl * 257 + col] = v;
    }
    __syncthreads();

    float* Cws = (float*)(ws + C_OFF);
    float* Bws = (float*)(ws + BROW_OFF);
    float* Ows = (float*)(ws + OC_OFF);
    float* TCw = (float*)(ws + TC_OFF);
    float* TBw = (float*)(ws + TB_OFF);

    const int d = tid & 127, half = tid >> 7;
    const float* z0 = zs + (half * 2) * 257;
    const float* z1 = zs + (half * 2 + 1) * 257;
    float c0 = 0.f, c1 = 0.f, q0 = 0.f, q1 = 0.f, o0 = 0.f, o1 = 0.f;
    for (int k = 0; k < 256; k++) {
        float w1 = Wm1[k * 128 + d], w2 = Wm2[k * 128 + d], wo = Wo1[k * 128 + d];
        float za = z0[k], zb = z1[k];
        c0 += za * w1; c1 += zb * w1;
        q0 += za * w2; q1 += zb * w2;
        o0 += za * wo; o1 += zb * wo;
    }
    float gm = 0.f;
    for (int k = 0; k < 128; k++) gm += graph[b * 128 + k] * Wmg[k * 128 + d];
    const float cb = gm + bm1[d] + bm2[d] + bme[d] + bmg[d];
    const float ob = bo1[d] + bo2[d];
    const int r0 = row0 + half * 2;
    Cws[r0 * 128 + d] = c0 + cb;  Cws[(r0 + 1) * 128 + d] = c1 + cb;
    Bws[r0 * 128 + d] = q0;       Bws[(r0 + 1) * 128 + d] = q1;
    Ows[r0 * 128 + d] = o0 + ob;  Ows[(r0 + 1) * 128 + d] = o1 + ob;

    if (tid < 64) {
        int r4 = tid >> 4, t = (tid >> 1) & 7, which = tid & 1;
        const float* zr = zs + r4 * 257;
        const float* W = which ? Wt2 : Wt1;
        float acc = 0.f;
        for (int k = 0; k < 256; k++) acc += zr[k] * W[k * 8 + t];
        int rg = row0 + r4;
        if (which == 0) {
            float gt = 0.f;
            for (int k = 0; k < 128; k++) gt += graph[b * 128 + k] * Wtg[k * 8 + t];
            TCw[rg * 8 + t] = acc + gt + bt1[t] + bt2[t] + bte[t] + btg[t];
        } else {
            TBw[rg * 8 + t] = acc;
        }
    }
}

// ---------------------------------------------------------------------------
// k2: fused edge GEMM (msg_e 128 cols + te 8 cols, bf16 MFMA 16x16x32)
//     + tri relu-store + masked max over senders (atomic, C deferred to k3).
// grid (32 jt, 16 ic, 2 b) = 1024 blocks x 256 thr (4 waves). Wave: 8 senders.
// LDS: 36.9 KB (weights; overlaid by the reduce buffer) -> 4 blocks/CU.
// ---------------------------------------------------------------------------
__global__ __launch_bounds__(256, 4) void k2_main(
    const float* __restrict__ edge, const float* __restrict__ adj,
    char* __restrict__ ws, float* __restrict__ out)
{
    __shared__ __align__(16) unsigned short wp[16 * 144 * 8];  // 36864 B
    const int tid = threadIdx.x;
    const int jt = blockIdx.x, ic = blockIdx.y, b = blockIdx.z;
    const int j0 = jt * 16, i0 = ic * 32;

    {   // stage packed weights to LDS: 2304 float4, 9 per thread
        const float4* src = (const float4*)(ws + WPACK_OFF);
        float4* dst = (float4*)wp;
        #pragma unroll
        for (int e = 0; e < 9; e++) dst[e * 256 + tid] = src[e * 256 + tid];
    }
    __syncthreads();

    const int lane = tid & 63, wave = tid >> 6;
    const int quad = lane >> 4, l15 = lane & 15;
    const float* Bws = (const float*)(ws + BROW_OFF);
    const float* TCw = (const float*)(ws + TC_OFF);
    const float* TBw = (const float*)(ws + TB_OFF);
    unsigned* M1 = (unsigned*)(ws + M1_OFF);
    int* Zfl = (int*)(ws + Z_OFF);

    const int jb = j0 + quad * 4;
    // triplet C fragment only (4 regs)
    float TCf[4];
    #pragma unroll
    for (int r = 0; r < 4; r++)
        TCf[r] = (l15 < 8) ? TCw[(b * 512 + jb + r) * 8 + l15] : 0.f;

    float Mx[8][4];
    #pragma unroll
    for (int nt = 0; nt < 8; nt++)
        #pragma unroll
        for (int r = 0; r < 4; r++) Mx[nt][r] = -INFINITY;
    int anyz[4] = {0, 0, 0, 0};

    const s16x8* wp8 = (const s16x8*)wp;

    for (int ii = 0; ii < 8; ii++) {
        const int ig = i0 + wave * 8 + ii;
        const float* erow = edge + ((b * 512 + ig) * 512 + j0 + l15) * 128 + quad * 8;
        s16x8 af[4];
        #pragma unroll
        for (int s = 0; s < 4; s++) {
            float4 p = *(const float4*)(erow + s * 32);
            float4 q = *(const float4*)(erow + s * 32 + 4);
            s16x8 a;
            a[0] = (short)f2bf(p.x); a[1] = (short)f2bf(p.y);
            a[2] = (short)f2bf(p.z); a[3] = (short)f2bf(p.w);
            a[4] = (short)f2bf(q.x); a[5] = (short)f2bf(q.y);
            a[6] = (short)f2bf(q.z); a[7] = (short)f2bf(q.w);
            af[s] = a;
        }
        float adjv[4];
        const int arow = (b * 512 + ig) * 512 + jb;
        #pragma unroll
        for (int r = 0; r < 4; r++) adjv[r] = adj[arow + r];
        float brw[8];
        const int br0 = (b * 512 + ig) * 128;
        #pragma unroll
        for (int nt = 0; nt < 8; nt++) brw[nt] = Bws[br0 + nt * 16 + l15];
        const float tb = (l15 < 8) ? TBw[(b * 512 + ig) * 8 + l15] : 0.f;

        f32x4 acc[9];
        #pragma unroll
        for (int nt = 0; nt < 9; nt++) acc[nt] = (f32x4){0.f, 0.f, 0.f, 0.f};
        #pragma unroll
        for (int s = 0; s < 4; s++) {
            const s16x8* wrow = wp8 + (4 * s + quad) * 144 + l15;
            #pragma unroll
            for (int nt = 0; nt < 9; nt++)
                acc[nt] = __builtin_amdgcn_mfma_f32_16x16x32_bf16(
                    af[s], wrow[nt * 16], acc[nt], 0, 0, 0);
        }
        // masked-max epilogue (C deferred to k3): candidate acc+brw iff adj==1
        #pragma unroll
        for (int r = 0; r < 4; r++) {
            const int isz = (adjv[r] == 0.f);
            anyz[r] |= isz;
            #pragma unroll
            for (int nt = 0; nt < 8; nt++) {
                float v = isz ? -INFINITY : (acc[nt][r] + brw[nt]);
                Mx[nt][r] = fmaxf(Mx[nt][r], v);
            }
        }
        // tri relu-store: tri[b, ig, jb+r, t=l15]
        if (l15 < 8) {
            float* tout = out + OUT_TRI + ((b * 512 + ig) * 512 + jb) * 8 + l15;
            #pragma unroll
            for (int r = 0; r < 4; r++) {
                float tv = acc[8][r] + TCf[r] + tb;
                tout[r * 8] = fmaxf(tv, 0.f);
            }
        }
    }

    // zero-adjacency flags (one lane per (quad,r) j-row)
    if (l15 == 0) {
        #pragma unroll
        for (int r = 0; r < 4; r++)
            if (anyz[r]) atomicOr(&Zfl[b * 512 + jb + r], 1);
    }

    // cross-wave max reduce in LDS (overlaid on wp) -> atomics
    __syncthreads();  // all waves done reading wp
    float* red = (float*)wp;  // 4*2048 floats = 32768 B <= 36864
    #pragma unroll
    for (int nt = 0; nt < 8; nt++)
        #pragma unroll
        for (int r = 0; r < 4; r++)
            red[wave * 2048 + (quad * 4 + r) * 128 + nt * 16 + l15] = Mx[nt][r];
    __syncthreads();
    #pragma unroll
    for (int e = 0; e < 8; e++) {
        int idx = e * 256 + tid;            // jl*128 + d
        float m = red[idx];
        #pragma unroll
        for (int w = 1; w < 4; w++) m = fmaxf(m, red[w * 2048 + idx]);
        if (m > -INFINITY) {
            int jl = idx >> 7, d = idx & 127;
            atomicMax(&M1[(b * 512 + j0 + jl) * 128 + d], fmap(m));
        }
    }
}

// ---------------------------------------------------------------------------
// k3: msgs = max(unmap(M1)+C, anyzero?0:-inf); ret = Oc + msgs @ Wo2
// grid 1024 (one per (b,j)) x 128 thr (d)
// ---------------------------------------------------------------------------
__global__ __launch_bounds__(128) void k3_final(
    const char* __restrict__ ws, const float* __restrict__ Wo2,
    float* __restrict__ out)
{
    __shared__ float ms[128];
    const int bj = blockIdx.x, d = threadIdx.x;
    const int b = bj >> 9, j = bj & 511;
    const unsigned* M1 = (const unsigned*)(ws + M1_OFF);
    const int* Zfl = (const int*)(ws + Z_OFF);
    const float* Cws = (const float*)(ws + C_OFF);
    const float* Ows = (const float*)(ws + OC_OFF);

    const int rj = b * 512 + j;
    float m1 = funmap(M1[rj * 128 + d]);           // NaN if untouched
    float c = Cws[rj * 128 + d];
    float alt = Zfl[rj] ? 0.f : -INFINITY;
    float m = fmaxf(m1 + c, alt);                  // fmax drops NaN operand
    ms[d] = m;
    __syncthreads();
    float acc = Ows[rj * 128 + d];
    #pragma unroll 8
    for (int k = 0; k < 128; k++) acc += ms[k] * Wo2[k * 128 + d];
    out[rj * 128 + d] = acc;
}

extern "C" void kernel_launch(void* const* d_in, const int* in_sizes, int n_in,
                              void* d_out, int out_size, void* d_ws, size_t ws_size,
                              hipStream_t stream) {
    const float* node   = (const float*)d_in[0];
    const float* edge   = (const float*)d_in[1];
    const float* graph  = (const float*)d_in[2];
    const float* adj    = (const float*)d_in[3];
    const float* hidden = (const float*)d_in[4];
    const float* Wm1 = (const float*)d_in[5];  const float* bm1 = (const float*)d_in[6];
    const float* Wm2 = (const float*)d_in[7];  const float* bm2 = (const float*)d_in[8];
    const float* Wme = (const float*)d_in[9];  const float* bme = (const float*)d_in[10];
    const float* Wmg = (const float*)d_in[11]; const float* bmg = (const float*)d_in[12];
    const float* Wo1 = (const float*)d_in[13]; const float* bo1 = (const float*)d_in[14];
    const float* Wo2 = (const float*)d_in[15]; const float* bo2 = (const float*)d_in[16];
    const float* Wt1 = (const float*)d_in[17]; const float* bt1 = (const float*)d_in[18];
    const float* Wt2 = (const float*)d_in[19]; const float* bt2 = (const float*)d_in[20];
    const float* Wte = (const float*)d_in[21]; const float* bte = (const float*)d_in[22];
    const float* Wtg = (const float*)d_in[23]; const float* btg = (const float*)d_in[24];
    float* out = (float*)d_out;
    char* ws = (char*)d_ws;

    // zero the atomic-max + zero-flag region (ws is re-poisoned each call)
    hipMemsetAsync(ws + M1_OFF, 0, (Z_OFF - M1_OFF) + 2 * 512 * sizeof(int), stream);

    k0_precompute<<<dim3(257), dim3(256), 0, stream>>>(
        node, hidden, graph, Wm1, Wm2, Wo1, Wmg, Wt1, Wt2, Wtg, Wme, Wte,
        bm1, bm2, bme, bmg, bo1, bo2, bt1, bt2, bte, btg, ws);
    k2_main<<<dim3(32, 16, 2), dim3(256), 0, stream>>>(edge, adj, ws, out);
    k3_final<<<dim3(1024), dim3(128), 0, stream>>>(ws, Wo2, out);
}

// Round 3
// 495.878 us; speedup vs baseline: 1.3266x; 1.3266x over previous
//
#include <hip/hip_runtime.h>
#include <hip/hip_bf16.h>

// Problem constants
#define NB 2
#define NN 512
#define HH 128
#define DD 128
#define TT 8

// ws layout (bytes). Total 18,485,248 B (r1 proved >= 18,452,480).
#define WPACK_OFF 0        // ushort[16*144*8] = 36864 B, bf16 [k/8][n][k%8]
#define C_OFF     36864    // float[2*512*128]  z@Wm1 + g@Wmg + (bm1+bm2+bme+bmg)
#define BROW_OFF  561152   // float[2*512*128]  z@Wm2
#define TC_OFF    1085440  // float[2*512*8]    z@Wt1 + g@Wtg + (bt1+bt2+bte+btg)
#define TB_OFF    1118208  // float[2*512*8]    z@Wt2
#define OC_OFF    1150976  // float[2*512*128]  z@Wo1 + bo1 + bo2
#define PART_OFF  1675264  // float[2*8*512*128] partial max (no C) per 64-sender chunk
#define ZF_OFF    18452480 // int[2*8*512]      1 if any sender in chunk has adj==0

#define OUT_TRI   131072   // float offset of tri_msgs in d_out

typedef float f32x4 __attribute__((ext_vector_type(4)));
typedef short s16x8 __attribute__((ext_vector_type(8)));

__device__ __forceinline__ unsigned short f2bf(float f) {
    union { float f; unsigned int u; } x; x.f = f;
    unsigned int u = x.u;
    unsigned int r = (u + 0x7FFFu + ((u >> 16) & 1u)) >> 16;  // RNE
    return (unsigned short)r;
}

// ---------------------------------------------------------------------------
// k0: precompute small projections (fp32) + pack bf16 weights for MFMA
// ---------------------------------------------------------------------------
__global__ __launch_bounds__(256) void k0_precompute(
    const float* __restrict__ node, const float* __restrict__ hidden,
    const float* __restrict__ graph,
    const float* __restrict__ Wm1, const float* __restrict__ Wm2,
    const float* __restrict__ Wo1, const float* __restrict__ Wmg,
    const float* __restrict__ Wt1, const float* __restrict__ Wt2,
    const float* __restrict__ Wtg,
    const float* __restrict__ Wme, const float* __restrict__ Wte,
    const float* __restrict__ bm1, const float* __restrict__ bm2,
    const float* __restrict__ bme, const float* __restrict__ bmg,
    const float* __restrict__ bo1, const float* __restrict__ bo2,
    const float* __restrict__ bt1, const float* __restrict__ bt2,
    const float* __restrict__ bte, const float* __restrict__ btg,
    char* __restrict__ ws)
{
    const int bx = blockIdx.x, tid = threadIdx.x;
    if (bx == 256) {
        unsigned short* wp = (unsigned short*)(ws + WPACK_OFF);
        for (int idx = tid; idx < 16 * 144 * 8; idx += 256) {
            int j = idx & 7, tmp = idx >> 3;
            int n = tmp % 144, kq = tmp / 144;
            int k = kq * 8 + j;
            float v = 0.f;
            if (n < 128) v = Wme[k * 128 + n];
            else if (n < 136) v = Wte[k * 8 + (n - 128)];
            wp[idx] = f2bf(v);
        }
        return;
    }
    __shared__ float zs[4 * 257];
    const int row0 = bx * 4;
    const int b = row0 >> 9;
    #pragma unroll
    for (int e = 0; e < 4; e++) {
        int idx = e * 256 + tid;
        int rl = idx >> 8, col = idx & 255;
        float v = (col < 128) ? node[(row0 + rl) * 128 + col]
                              : hidden[(row0 + rl) * 128 + col - 128];
        zs[rl * 257 + col] = v;
    }
    __syncthreads();

    float* Cws = (float*)(ws + C_OFF);
    float* Bws = (float*)(ws + BROW_OFF);
    float* Ows = (float*)(ws + OC_OFF);
    float* TCw = (float*)(ws + TC_OFF);
    float* TBw = (float*)(ws + TB_OFF);

    const int d = tid & 127, half = tid >> 7;
    const float* z0 = zs + (half * 2) * 257;
    const float* z1 = zs + (half * 2 + 1) * 257;
    float c0 = 0.f, c1 = 0.f, q0 = 0.f, q1 = 0.f, o0 = 0.f, o1 = 0.f;
    for (int k = 0; k < 256; k++) {
        float w1 = Wm1[k * 128 + d], w2 = Wm2[k * 128 + d], wo = Wo1[k * 128 + d];
        float za = z0[k], zb = z1[k];
        c0 += za * w1; c1 += zb * w1;
        q0 += za * w2; q1 += zb * w2;
        o0 += za * wo; o1 += zb * wo;
    }
    float gm = 0.f;
    for (int k = 0; k < 128; k++) gm += graph[b * 128 + k] * Wmg[k * 128 + d];
    const float cb = gm + bm1[d] + bm2[d] + bme[d] + bmg[d];
    const float ob = bo1[d] + bo2[d];
    const int r0 = row0 + half * 2;
    Cws[r0 * 128 + d] = c0 + cb;  Cws[(r0 + 1) * 128 + d] = c1 + cb;
    Bws[r0 * 128 + d] = q0;       Bws[(r0 + 1) * 128 + d] = q1;
    Ows[r0 * 128 + d] = o0 + ob;  Ows[(r0 + 1) * 128 + d] = o1 + ob;

    if (tid < 64) {
        int r4 = tid >> 4, t = (tid >> 1) & 7, which = tid & 1;
        const float* zr = zs + r4 * 257;
        const float* W = which ? Wt2 : Wt1;
        float acc = 0.f;
        for (int k = 0; k < 256; k++) acc += zr[k] * W[k * 8 + t];
        int rg = row0 + r4;
        if (which == 0) {
            float gt = 0.f;
            for (int k = 0; k < 128; k++) gt += graph[b * 128 + k] * Wtg[k * 8 + t];
            TCw[rg * 8 + t] = acc + gt + bt1[t] + bt2[t] + bte[t] + btg[t];
        } else {
            TBw[rg * 8 + t] = acc;
        }
    }
}

// ---------------------------------------------------------------------------
// k2: fused edge GEMM + tri + masked max. B-fragments REGISTER-RESIDENT
// (zero per-iteration LDS traffic — r1/r2 were LDS-BW-bound at 36KB/iter).
// grid (32 jt, 8 ic, 2 b) = 512 blocks x 512 thr (8 waves).
// wave (g=wave>>2, sq=wave&3): g = d-half {tiles 0-3 | 4-7} (+tri tile on
// both, stored by g=1); sq = 16-sender subset. Block covers 64 senders.
// ---------------------------------------------------------------------------
__global__ __launch_bounds__(512, 2) void k2_main(
    const float* __restrict__ edge, const float* __restrict__ adj,
    char* __restrict__ ws, float* __restrict__ out)
{
    __shared__ float red[8][16][64];   // 32 KB: per-wave Mx dump
    __shared__ int zflag[16];
    const int tid = threadIdx.x;
    const int jt = blockIdx.x, ic = blockIdx.y, b = blockIdx.z;
    const int j0 = jt * 16, i0 = ic * 64;

    const int lane = tid & 63, wave = tid >> 6;
    const int g = wave >> 2, sq = wave & 3;
    const int quad = lane >> 4, l15 = lane & 15;
    const int ntbase = g * 4;

    if (tid < 16) zflag[tid] = 0;
    __syncthreads();

    const float* Bws = (const float*)(ws + BROW_OFF);
    const float* TCw = (const float*)(ws + TC_OFF);
    const float* TBw = (const float*)(ws + TB_OFF);
    const s16x8* wp8 = (const s16x8*)(ws + WPACK_OFF);
    float* part = (float*)(ws + PART_OFF);
    int* Zws = (int*)(ws + ZF_OFF);

    // B fragments -> registers (loop-invariant). 5 tiles x 4 k-steps.
    // tile ntl 0..3 -> nt = ntbase+ntl (D cols); ntl 4 -> nt 8 (tri cols).
    s16x8 Bf[5][4];
    #pragma unroll
    for (int s = 0; s < 4; s++) {
        #pragma unroll
        for (int ntl = 0; ntl < 5; ntl++) {
            int nt = (ntl < 4) ? (ntbase + ntl) : 8;
            Bf[ntl][s] = wp8[(4 * s + quad) * 144 + nt * 16 + l15];
        }
    }

    const int jb = j0 + quad * 4;
    float TCf[4];
    #pragma unroll
    for (int r = 0; r < 4; r++)
        TCf[r] = (l15 < 8) ? TCw[(b * 512 + jb + r) * 8 + l15] : 0.f;

    float Mx[4][4];
    #pragma unroll
    for (int ntl = 0; ntl < 4; ntl++)
        #pragma unroll
        for (int r = 0; r < 4; r++) Mx[ntl][r] = -INFINITY;
    int anyz[4] = {0, 0, 0, 0};

    for (int ii = 0; ii < 16; ii++) {
        const int ig = i0 + sq * 16 + ii;
        const float* erow = edge + ((b * 512 + ig) * 512 + j0 + l15) * 128 + quad * 8;
        s16x8 af[4];
        #pragma unroll
        for (int s = 0; s < 4; s++) {
            float4 p = *(const float4*)(erow + s * 32);
            float4 q = *(const float4*)(erow + s * 32 + 4);
            s16x8 a;
            a[0] = (short)f2bf(p.x); a[1] = (short)f2bf(p.y);
            a[2] = (short)f2bf(p.z); a[3] = (short)f2bf(p.w);
            a[4] = (short)f2bf(q.x); a[5] = (short)f2bf(q.y);
            a[6] = (short)f2bf(q.z); a[7] = (short)f2bf(q.w);
            af[s] = a;
        }
        float adjv[4];
        const int arow = (b * 512 + ig) * 512 + jb;
        #pragma unroll
        for (int r = 0; r < 4; r++) adjv[r] = adj[arow + r];
        float brw[4];
        const int br0 = (b * 512 + ig) * 128;
        #pragma unroll
        for (int ntl = 0; ntl < 4; ntl++)
            brw[ntl] = Bws[br0 + (ntbase + ntl) * 16 + l15];
        const float tb = (l15 < 8) ? TBw[(b * 512 + ig) * 8 + l15] : 0.f;

        f32x4 acc[5];
        #pragma unroll
        for (int ntl = 0; ntl < 5; ntl++) acc[ntl] = (f32x4){0.f, 0.f, 0.f, 0.f};
        #pragma unroll
        for (int s = 0; s < 4; s++) {
            #pragma unroll
            for (int ntl = 0; ntl < 5; ntl++)
                acc[ntl] = __builtin_amdgcn_mfma_f32_16x16x32_bf16(
                    af[s], Bf[ntl][s], acc[ntl], 0, 0, 0);
        }
        // masked-max epilogue (C deferred to k3)
        #pragma unroll
        for (int r = 0; r < 4; r++) {
            const int isz = (adjv[r] == 0.f);
            anyz[r] |= isz;
            #pragma unroll
            for (int ntl = 0; ntl < 4; ntl++) {
                float v = isz ? -INFINITY : (acc[ntl][r] + brw[ntl]);
                Mx[ntl][r] = fmaxf(Mx[ntl][r], v);
            }
        }
        // tri relu-store (only g==1 stores; both compute for uniformity)
        if (g == 1 && l15 < 8) {
            float* tout = out + OUT_TRI + ((b * 512 + ig) * 512 + jb) * 8 + l15;
            #pragma unroll
            for (int r = 0; r < 4; r++) {
                float tv = acc[4][r] + TCf[r] + tb;
                tout[r * 8] = fmaxf(tv, 0.f);
            }
        }
        if ((ii & 3) == 3) __syncthreads();  // keep A-load twins cache-aligned
    }

    // flags + Mx dump
    if (g == 0 && l15 == 0) {
        #pragma unroll
        for (int r = 0; r < 4; r++)
            if (anyz[r]) atomicOr(&zflag[quad * 4 + r], 1);
    }
    #pragma unroll
    for (int ntl = 0; ntl < 4; ntl++)
        #pragma unroll
        for (int r = 0; r < 4; r++)
            red[wave][quad * 4 + r][ntl * 16 + l15] = Mx[ntl][r];
    __syncthreads();

    // final reduce over 4 sender-subsets -> partial[b][ic][j][d]
    {
        const int q = tid;               // one float4 per thread, 512 total
        const int j = q >> 5, dq = q & 31;
        const int g2 = dq >> 4, c0 = (dq & 15) * 4;
        const float* r0p = &red[g2 * 4][j][c0];
        float4 m = *(const float4*)r0p;
        #pragma unroll
        for (int w = 1; w < 4; w++) {
            const float4 o = *(const float4*)&red[g2 * 4 + w][j][c0];
            m.x = fmaxf(m.x, o.x); m.y = fmaxf(m.y, o.y);
            m.z = fmaxf(m.z, o.z); m.w = fmaxf(m.w, o.w);
        }
        *(float4*)(part + ((b * 8 + ic) * 512 + j0 + j) * 128 + dq * 4) = m;
    }
    if (tid < 16) Zws[(b * 8 + ic) * 512 + j0 + tid] = zflag[tid];
}

// ---------------------------------------------------------------------------
// k3: msgs = max(max_ic partial + C, anyzero?0:-inf); ret = Oc + msgs @ Wo2
// grid 1024 (one per (b,j)) x 128 thr (d)
// ---------------------------------------------------------------------------
__global__ __launch_bounds__(128) void k3_final(
    const char* __restrict__ ws, const float* __restrict__ Wo2,
    float* __restrict__ out)
{
    __shared__ float ms[128];
    const int bj = blockIdx.x, d = threadIdx.x;
    const int b = bj >> 9, j = bj & 511;
    const float* part = (const float*)(ws + PART_OFF);
    const int* Zws = (const int*)(ws + ZF_OFF);
    const float* Cws = (const float*)(ws + C_OFF);
    const float* Ows = (const float*)(ws + OC_OFF);

    const int rj = b * 512 + j;
    float m = -INFINITY;
    int zf = 0;
    #pragma unroll
    for (int ic = 0; ic < 8; ic++) {
        m = fmaxf(m, part[((b * 8 + ic) * 512 + j) * 128 + d]);
        zf |= Zws[(b * 8 + ic) * 512 + j];
    }
    float c = Cws[rj * 128 + d];
    float mm = fmaxf(m + c, zf ? 0.f : -INFINITY);
    ms[d] = mm;
    __syncthreads();
    float acc = Ows[rj * 128 + d];
    #pragma unroll 8
    for (int k = 0; k < 128; k++) acc += ms[k] * Wo2[k * 128 + d];
    out[rj * 128 + d] = acc;
}

extern "C" void kernel_launch(void* const* d_in, const int* in_sizes, int n_in,
                              void* d_out, int out_size, void* d_ws, size_t ws_size,
                              hipStream_t stream) {
    const float* node   = (const float*)d_in[0];
    const float* edge   = (const float*)d_in[1];
    const float* graph  = (const float*)d_in[2];
    const float* adj    = (const float*)d_in[3];
    const float* hidden = (const float*)d_in[4];
    const float* Wm1 = (const float*)d_in[5];  const float* bm1 = (const float*)d_in[6];
    const float* Wm2 = (const float*)d_in[7];  const float* bm2 = (const float*)d_in[8];
    const float* Wme = (const float*)d_in[9];  const float* bme = (const float*)d_in[10];
    const float* Wmg = (const float*)d_in[11]; const float* bmg = (const float*)d_in[12];
    const float* Wo1 = (const float*)d_in[13]; const float* bo1 = (const float*)d_in[14];
    const float* Wo2 = (const float*)d_in[15]; const float* bo2 = (const float*)d_in[16];
    const float* Wt1 = (const float*)d_in[17]; const float* bt1 = (const float*)d_in[18];
    const float* Wt2 = (const float*)d_in[19]; const float* bt2 = (const float*)d_in[20];
    const float* Wte = (const float*)d_in[21]; const float* bte = (const float*)d_in[22];
    const float* Wtg = (const float*)d_in[23]; const float* btg = (const float*)d_in[24];
    float* out = (float*)d_out;
    char* ws = (char*)d_ws;

    k0_precompute<<<dim3(257), dim3(256), 0, stream>>>(
        node, hidden, graph, Wm1, Wm2, Wo1, Wmg, Wt1, Wt2, Wtg, Wme, Wte,
        bm1, bm2, bme, bmg, bo1, bo2, bt1, bt2, bte, btg, ws);
    k2_main<<<dim3(32, 8, 2), dim3(512), 0, stream>>>(edge, adj, ws, out);
    k3_final<<<dim3(1024), dim3(128), 0, stream>>>(ws, Wo2, out);
}